// Round 11
// baseline (135.291 us; speedup 1.0000x reference)
//
#include <hip/hip_runtime.h>
#include <math.h>

#define NROWS 65536
#define D 64
#define K 1024
#define Q 4               // code quarters
#define CPB 256           // codes per block (K/Q)
#define RPB 256           // rows per block (8 waves x 32)
#define T1 512
#define TAU_S 0.005f      // certification gap in s-units (dist gap = 2x)
#define LOSS_SCALE (1.25f / (65536.0f * 64.0f))

typedef short bf16x8 __attribute__((ext_vector_type(8)));
typedef float f32x4 __attribute__((ext_vector_type(4)));
typedef __attribute__((address_space(1))) const unsigned int glb_u32;
typedef __attribute__((address_space(3))) unsigned int lds_u32;

__device__ inline unsigned short f2bf(float f) {
    unsigned int u = __float_as_uint(f);
    unsigned int r = u + 0x7fffu + ((u >> 16) & 1u);   // RN-even
    return (unsigned short)(r >> 16);
}
__device__ inline float bf2f(unsigned short h) {
    return __uint_as_float(((unsigned int)h) << 16);
}
__device__ inline void cvt8(const float4& a, const float4& b, bf16x8& h, bf16x8& l) {
    float f[8] = {a.x, a.y, a.z, a.w, b.x, b.y, b.z, b.w};
#pragma unroll
    for (int j = 0; j < 8; ++j) {
        unsigned short hb = f2bf(f[j]);
        h[j] = (short)hb;
        l[j] = (short)f2bf(f[j] - bf2f(hb));
    }
}

#define MFMA __builtin_amdgcn_mfma_f32_16x16x32_bf16

// prep: half-norms Ch + E limbs in MFMA FRAGMENT order + zero loss.
// Fragment (ct, kt, limb): lane l holds code ct*16+(l&15), dims kt*32+(l>>4)*8..+8.
// Eswz unit index = (ct*4 + kt*2 + limb)*64 + lane.   (verified: R7-R10 passed)
__global__ void vq_prep(const float* __restrict__ E, float* __restrict__ Ch,
                        bf16x8* __restrict__ Eswz, float* __restrict__ lossp) {
    int k = blockIdx.x * blockDim.x + threadIdx.x;
    if (k == 0) *lossp = 0.f;
    if (k >= K) return;
    const float4* ev = (const float4*)(E + (size_t)k * D);
    float4 v4[16];
    float s = 0.f;
#pragma unroll
    for (int p = 0; p < 16; ++p) {
        float4 v = ev[p];
        v4[p] = v;
        s = fmaf(v.x, v.x, s); s = fmaf(v.y, v.y, s);
        s = fmaf(v.z, v.z, s); s = fmaf(v.w, v.w, s);
    }
    Ch[k] = 0.5f * s;
    int ct = k >> 4, li = k & 15;
#pragma unroll
    for (int kt = 0; kt < 2; ++kt)
#pragma unroll
        for (int o = 0; o < 4; ++o) {
            int lane = li + 16 * o;
            bf16x8 h, l;
            cvt8(v4[kt * 8 + o * 2], v4[kt * 8 + o * 2 + 1], h, l);
            Eswz[(size_t)(ct * 4 + kt * 2 + 0) * 64 + lane] = h;
            Eswz[(size_t)(ct * 4 + kt * 2 + 1) * 64 + lane] = l;
        }
}

// kernel 1: per (row-group, code-quarter) partial top-2.  Stage once, then a
// single barrier-free straight-line run of 192 MFMA + 64 ds_read per wave.
__global__ __launch_bounds__(T1, 4) void vq_part(
    const float* __restrict__ X, const float* __restrict__ Chg,
    const bf16x8* __restrict__ Eswz,
    float* __restrict__ pm, float* __restrict__ pm2, int* __restrict__ pk)
{
    __shared__ bf16x8 sBuf[4096];          // 64 KB: this quarter's 256 codes

    const int t    = threadIdx.x;
    const int w    = t >> 6;
    const int lane = t & 63;
    const int l15  = lane & 15;
    const int l4   = lane >> 4;
    const int q    = blockIdx.x & 3;       // code quarter
    const int rg   = blockIdx.x >> 2;      // row group (256 rows)

    // ---- stage this quarter's fragments (linear DMA; layout pre-swizzled) ----
#pragma unroll
    for (int i = 0; i < 8; ++i) {
        int s = w * 8 + i;
        const bf16x8* gs = Eswz + ((size_t)q * 4096 + s * 64 + lane);
        __builtin_amdgcn_global_load_lds((glb_u32*)gs, (lds_u32*)(sBuf + s * 64), 16, 0, 0);
    }

    // ---- A fragments while the DMA flies ----
    const float4* Xg4 = (const float4*)X;
    bf16x8 ah[2][2], al[2][2];
#pragma unroll
    for (int rt = 0; rt < 2; ++rt) {
        size_t ab = ((size_t)rg * RPB + w * 32 + rt * 16 + l15) * 16;
#pragma unroll
        for (int kt = 0; kt < 2; ++kt) {
            float4 fa = Xg4[ab + kt * 8 + l4 * 2];
            float4 fb = Xg4[ab + kt * 8 + l4 * 2 + 1];
            cvt8(fa, fb, ah[rt][kt], al[rt][kt]);
        }
    }

    float m[2][4], m2[2][4]; int bk[2][4];
#pragma unroll
    for (int rt = 0; rt < 2; ++rt)
#pragma unroll
        for (int r = 0; r < 4; ++r) { m[rt][r] = -INFINITY; m2[rt][r] = -INFINITY; bk[rt][r] = 0; }

    __syncthreads();   // one barrier: DMA drained (vmcnt 0), buffer visible

    // ---- barrier-free main run: 16 code-tiles, fully unrolled ----
#pragma unroll
    for (int ct = 0; ct < 16; ++ct) {
        bf16x8 bh0 = sBuf[ct * 256 +   0 + lane];
        bf16x8 bl0 = sBuf[ct * 256 +  64 + lane];
        bf16x8 bh1 = sBuf[ct * 256 + 128 + lane];
        bf16x8 bl1 = sBuf[ct * 256 + 192 + lane];
        float ce = Chg[(q * 16 + ct) * 16 + l15];

        f32x4 a0 = {-ce, -ce, -ce, -ce};   // rows rt0, s = dot - 0.5||e||^2
        f32x4 a1 = {-ce, -ce, -ce, -ce};   // rows rt1
        a0 = MFMA(ah[0][0], bh0, a0, 0, 0, 0); a1 = MFMA(ah[1][0], bh0, a1, 0, 0, 0);
        a0 = MFMA(ah[0][1], bh1, a0, 0, 0, 0); a1 = MFMA(ah[1][1], bh1, a1, 0, 0, 0);
        a0 = MFMA(al[0][0], bh0, a0, 0, 0, 0); a1 = MFMA(al[1][0], bh0, a1, 0, 0, 0);
        a0 = MFMA(al[0][1], bh1, a0, 0, 0, 0); a1 = MFMA(al[1][1], bh1, a1, 0, 0, 0);
        a0 = MFMA(ah[0][0], bl0, a0, 0, 0, 0); a1 = MFMA(ah[1][0], bl0, a1, 0, 0, 0);
        a0 = MFMA(ah[0][1], bl1, a0, 0, 0, 0); a1 = MFMA(ah[1][1], bl1, a1, 0, 0, 0);

        const int kk = q * CPB + ct * 16 + l15;
#pragma unroll
        for (int r = 0; r < 4; ++r) {
            float v;
            v = a0[r];
            m2[0][r] = __builtin_amdgcn_fmed3f(m2[0][r], m[0][r], v);
            bk[0][r] = (v > m[0][r]) ? kk : bk[0][r];
            m[0][r]  = fmaxf(m[0][r], v);
            v = a1[r];
            m2[1][r] = __builtin_amdgcn_fmed3f(m2[1][r], m[1][r], v);
            bk[1][r] = (v > m[1][r]) ? kk : bk[1][r];
            m[1][r]  = fmaxf(m[1][r], v);
        }
    }

    // ---- per-row top2 reduce across 16 col-lanes, write partials ----
#pragma unroll
    for (int rt = 0; rt < 2; ++rt)
#pragma unroll
        for (int r = 0; r < 4; ++r) {
            float mm = m[rt][r], mm2 = m2[rt][r]; int kk = bk[rt][r];
#pragma unroll
            for (int off = 1; off < 16; off <<= 1) {
                float om  = __shfl_xor(mm,  off, 64);
                float om2 = __shfl_xor(mm2, off, 64);
                int   ok  = __shfl_xor(kk,  off, 64);
                mm2 = fmaxf(fmaxf(mm2, om2), fminf(mm, om));
                if (om > mm || (om == mm && ok < kk)) { mm = om; kk = ok; }
            }
            if (l15 == 0) {
                int grow = rg * RPB + w * 32 + rt * 16 + l4 * 4 + r;
                pm [q * NROWS + grow] = mm;
                pm2[q * NROWS + grow] = mm2;
                pk [q * NROWS + grow] = kk;
            }
        }
}

// kernel 2: combine quarters, gather output + loss, exact re-rank of ties.
__global__ __launch_bounds__(256) void vq_comb(
    const float* __restrict__ X, const float* __restrict__ E,
    const float* __restrict__ Chg,
    const float* __restrict__ pm, const float* __restrict__ pm2,
    const int* __restrict__ pk,
    float* __restrict__ out, float* __restrict__ lossp)
{
    __shared__ int sFlag[256];
    __shared__ int sNf;
    const int t = threadIdx.x, w = t >> 6, lane = t & 63;
    const int row = blockIdx.x * 256 + t;
    if (t == 0) sNf = 0;
    __syncthreads();

    const float4* Xg4 = (const float4*)X;
    const float4* Eg4 = (const float4*)E;

    // combine 4 quarter partials (ascending q => tie -> lower code)
    float top = -INFINITY, sec = -INFINITY, m2w = -INFINITY; int kw = 0;
#pragma unroll
    for (int q = 0; q < 4; ++q) {
        float mq  = pm [q * NROWS + row];
        float m2q = pm2[q * NROWS + row];
        int   kq  = pk [q * NROWS + row];
        if (mq > top) { sec = top; top = mq; kw = kq; m2w = m2q; }
        else sec = fmaxf(sec, mq);
    }
    sec = fmaxf(sec, m2w);

    float ls = 0.f;
    bool flag = (top - sec < TAU_S);
    if (flag) {
        int pos = atomicAdd(&sNf, 1);
        sFlag[pos] = t;
    } else {
        const float4* eq = Eg4 + (size_t)kw * 16;
        const float4* xr = Xg4 + (size_t)row * 16;
        float4* orow = (float4*)out + (size_t)row * 16;
#pragma unroll
        for (int u = 0; u < 16; ++u) {
            float4 qv = eq[u], xv = xr[u];
            orow[u] = qv;
            float dx = qv.x - xv.x; ls = fmaf(dx, dx, ls);
            float dy = qv.y - xv.y; ls = fmaf(dy, dy, ls);
            float dz = qv.z - xv.z; ls = fmaf(dz, dz, ls);
            float dw = qv.w - xv.w; ls = fmaf(dw, dw, ls);
        }
    }
#pragma unroll
    for (int off = 32; off > 0; off >>= 1) ls += __shfl_down(ls, off, 64);
    if (lane == 0) atomicAdd(lossp, ls * LOSS_SCALE);
    __syncthreads();

    // exact fp32 re-rank of flagged rows (one wave per row)
    int nf = sNf;
    for (int i = w; i < nf; i += 4) {
        int row2 = blockIdx.x * 256 + sFlag[i];
        const float4* xr = Xg4 + (size_t)row2 * 16;
        float bs = -INFINITY; int bki = 0;
#pragma unroll 1
        for (int jj = 0; jj < 16; ++jj) {
            int kq = jj * 64 + lane;
            const float4* er = Eg4 + (size_t)kq * 16;
            float a0 = 0.f, a1 = 0.f, a2 = 0.f, a3 = 0.f;
#pragma unroll
            for (int p = 0; p < 16; p += 4) {
                float4 xv0 = xr[p],     e0 = er[p];
                float4 xv1 = xr[p + 1], e1 = er[p + 1];
                float4 xv2 = xr[p + 2], e2 = er[p + 2];
                float4 xv3 = xr[p + 3], e3 = er[p + 3];
                a0 = fmaf(xv0.x, e0.x, a0); a0 = fmaf(xv0.y, e0.y, a0);
                a0 = fmaf(xv0.z, e0.z, a0); a0 = fmaf(xv0.w, e0.w, a0);
                a1 = fmaf(xv1.x, e1.x, a1); a1 = fmaf(xv1.y, e1.y, a1);
                a1 = fmaf(xv1.z, e1.z, a1); a1 = fmaf(xv1.w, e1.w, a1);
                a2 = fmaf(xv2.x, e2.x, a2); a2 = fmaf(xv2.y, e2.y, a2);
                a2 = fmaf(xv2.z, e2.z, a2); a2 = fmaf(xv2.w, e2.w, a2);
                a3 = fmaf(xv3.x, e3.x, a3); a3 = fmaf(xv3.y, e3.y, a3);
                a3 = fmaf(xv3.z, e3.z, a3); a3 = fmaf(xv3.w, e3.w, a3);
            }
            float sv = ((a0 + a1) + (a2 + a3)) - Chg[kq];
            if (sv > bs) { bs = sv; bki = kq; }
        }
#pragma unroll
        for (int off = 1; off < 64; off <<= 1) {
            float ob = __shfl_xor(bs, off, 64);
            int  okk = __shfl_xor(bki, off, 64);
            if (ob > bs || (ob == bs && okk < bki)) { bs = ob; bki = okk; }
        }
        if (lane < 16) {
            float4 qv = Eg4[(size_t)bki * 16 + lane];
            float4 xv = xr[lane];
            ((float4*)out)[(size_t)row2 * 16 + lane] = qv;
            float dl = 0.f;
            float dx = qv.x - xv.x; dl = fmaf(dx, dx, dl);
            float dy = qv.y - xv.y; dl = fmaf(dy, dy, dl);
            float dz = qv.z - xv.z; dl = fmaf(dz, dz, dl);
            float dw = qv.w - xv.w; dl = fmaf(dw, dw, dl);
#pragma unroll
            for (int off = 1; off < 16; off <<= 1) dl += __shfl_xor(dl, off, 16);
            if (lane == 0) atomicAdd(lossp, dl * LOSS_SCALE);
        }
    }
}

extern "C" void kernel_launch(void* const* d_in, const int* in_sizes, int n_in,
                              void* d_out, int out_size, void* d_ws, size_t ws_size,
                              hipStream_t stream) {
    const float* X = (const float*)d_in[0];        // [64,1024,64] f32
    const float* E = (const float*)d_in[1];        // [1024,64] f32
    float* out   = (float*)d_out;
    float* lossp = out + (size_t)NROWS * D;

    // ws layout: Ch (4 KB) | Eswz (256 KB) | pm (1 MB) | pm2 (1 MB) | pk (1 MB)
    float*  Ch   = (float*)d_ws;
    bf16x8* Eswz = (bf16x8*)((char*)d_ws + 4096);
    float*  pm   = (float*)((char*)d_ws + 4096 + 262144);
    float*  pm2  = pm + (size_t)Q * NROWS;
    int*    pk   = (int*)(pm2 + (size_t)Q * NROWS);

    vq_prep<<<(K + 255) / 256, 256, 0, stream>>>(E, Ch, Eswz, lossp);

    vq_part<<<(NROWS / RPB) * Q, T1, 0, stream>>>(X, Ch, Eswz, pm, pm2, pk);

    vq_comb<<<NROWS / 256, 256, 0, stream>>>(X, E, Ch, pm, pm2, pk, out, lossp);
}

// Round 12
// 87.849 us; speedup vs baseline: 1.5400x; 1.5400x over previous
//
#include <hip/hip_runtime.h>
#include <math.h>

#define NROWS 65536
#define D 64
#define K 1024
#define Q 4               // code quarters
#define CPB 256           // codes per block (K/Q)
#define RPB 256           // rows per block (8 waves x 32)
#define T1 512
#define TAU_S 0.005f      // certification gap in s-units (dist gap = 2x)
#define LOSS_SCALE (1.25f / (65536.0f * 64.0f))

typedef short bf16x8 __attribute__((ext_vector_type(8)));
typedef float f32x4 __attribute__((ext_vector_type(4)));
typedef __attribute__((address_space(1))) const unsigned int glb_u32;
typedef __attribute__((address_space(3))) unsigned int lds_u32;

__device__ inline unsigned short f2bf(float f) {
    unsigned int u = __float_as_uint(f);
    unsigned int r = u + 0x7fffu + ((u >> 16) & 1u);   // RN-even
    return (unsigned short)(r >> 16);
}
__device__ inline float bf2f(unsigned short h) {
    return __uint_as_float(((unsigned int)h) << 16);
}
__device__ inline void cvt8(const float4& a, const float4& b, bf16x8& h, bf16x8& l) {
    float f[8] = {a.x, a.y, a.z, a.w, b.x, b.y, b.z, b.w};
#pragma unroll
    for (int j = 0; j < 8; ++j) {
        unsigned short hb = f2bf(f[j]);
        h[j] = (short)hb;
        l[j] = (short)f2bf(f[j] - bf2f(hb));
    }
}

#define MFMA __builtin_amdgcn_mfma_f32_16x16x32_bf16

// prep: half-norms Ch + E limbs in MFMA FRAGMENT order + zero loss.
// Fragment (ct, kt, limb): lane l holds code ct*16+(l&15), dims kt*32+(l>>4)*8..+8.
// Eswz unit index = (ct*4 + kt*2 + limb)*64 + lane.   (verified: R7-R11 passed)
__global__ void vq_prep(const float* __restrict__ E, float* __restrict__ Ch,
                        bf16x8* __restrict__ Eswz, float* __restrict__ lossp) {
    int k = blockIdx.x * blockDim.x + threadIdx.x;
    if (k == 0) *lossp = 0.f;
    if (k >= K) return;
    const float4* ev = (const float4*)(E + (size_t)k * D);
    float4 v4[16];
    float s = 0.f;
#pragma unroll
    for (int p = 0; p < 16; ++p) {
        float4 v = ev[p];
        v4[p] = v;
        s = fmaf(v.x, v.x, s); s = fmaf(v.y, v.y, s);
        s = fmaf(v.z, v.z, s); s = fmaf(v.w, v.w, s);
    }
    Ch[k] = 0.5f * s;
    int ct = k >> 4, li = k & 15;
#pragma unroll
    for (int kt = 0; kt < 2; ++kt)
#pragma unroll
        for (int o = 0; o < 4; ++o) {
            int lane = li + 16 * o;
            bf16x8 h, l;
            cvt8(v4[kt * 8 + o * 2], v4[kt * 8 + o * 2 + 1], h, l);
            Eswz[(size_t)(ct * 4 + kt * 2 + 0) * 64 + lane] = h;
            Eswz[(size_t)(ct * 4 + kt * 2 + 1) * 64 + lane] = l;
        }
}

// kernel 1: per (row-group, code-quarter) partial top-2.  Stage once (DMA),
// one barrier, then a barrier-free run; unroll 2 bounds the ds_read hoist
// window (full unroll spilled: R11, WRITE_SIZE 122 MB).
__global__ __launch_bounds__(T1, 4) void vq_part(
    const float* __restrict__ X, const float* __restrict__ Chg,
    const bf16x8* __restrict__ Eswz,
    float* __restrict__ pm, float* __restrict__ pm2, int* __restrict__ pk)
{
    __shared__ bf16x8 sBuf[4096];          // 64 KB: this quarter's 256 codes
    __shared__ float  sCh[CPB];            // 1 KB: this quarter's half-norms

    const int t    = threadIdx.x;
    const int w    = t >> 6;
    const int lane = t & 63;
    const int l15  = lane & 15;
    const int l4   = lane >> 4;
    const int q    = blockIdx.x & 3;       // code quarter
    const int rg   = blockIdx.x >> 2;      // row group (256 rows)

    // ---- stage this quarter's fragments (linear DMA; layout pre-swizzled) ----
#pragma unroll
    for (int i = 0; i < 8; ++i) {
        int s = w * 8 + i;
        const bf16x8* gs = Eswz + ((size_t)q * 4096 + s * 64 + lane);
        __builtin_amdgcn_global_load_lds((glb_u32*)gs, (lds_u32*)(sBuf + s * 64), 16, 0, 0);
    }
    if (t < CPB) sCh[t] = Chg[q * CPB + t];

    // ---- A fragments while the DMA flies ----
    const float4* Xg4 = (const float4*)X;
    bf16x8 ah[2][2], al[2][2];
#pragma unroll
    for (int rt = 0; rt < 2; ++rt) {
        size_t ab = ((size_t)rg * RPB + w * 32 + rt * 16 + l15) * 16;
#pragma unroll
        for (int kt = 0; kt < 2; ++kt) {
            float4 fa = Xg4[ab + kt * 8 + l4 * 2];
            float4 fb = Xg4[ab + kt * 8 + l4 * 2 + 1];
            cvt8(fa, fb, ah[rt][kt], al[rt][kt]);
        }
    }

    float m[2][4], m2[2][4]; int bk[2][4];
#pragma unroll
    for (int rt = 0; rt < 2; ++rt)
#pragma unroll
        for (int r = 0; r < 4; ++r) { m[rt][r] = -INFINITY; m2[rt][r] = -INFINITY; bk[rt][r] = 0; }

    __syncthreads();   // one barrier: DMA drained (vmcnt 0), sBuf/sCh visible

    // ---- barrier-free main run: 16 code-tiles, unroll 2 (bounded hoist) ----
#pragma unroll 2
    for (int ct = 0; ct < 16; ++ct) {
        bf16x8 bh0 = sBuf[ct * 256 +   0 + lane];
        bf16x8 bl0 = sBuf[ct * 256 +  64 + lane];
        bf16x8 bh1 = sBuf[ct * 256 + 128 + lane];
        bf16x8 bl1 = sBuf[ct * 256 + 192 + lane];
        float ce = sCh[ct * 16 + l15];

        f32x4 a0 = {-ce, -ce, -ce, -ce};   // rows rt0, s = dot - 0.5||e||^2
        f32x4 a1 = {-ce, -ce, -ce, -ce};   // rows rt1
        __builtin_amdgcn_s_setprio(1);
        a0 = MFMA(ah[0][0], bh0, a0, 0, 0, 0); a1 = MFMA(ah[1][0], bh0, a1, 0, 0, 0);
        a0 = MFMA(ah[0][1], bh1, a0, 0, 0, 0); a1 = MFMA(ah[1][1], bh1, a1, 0, 0, 0);
        a0 = MFMA(al[0][0], bh0, a0, 0, 0, 0); a1 = MFMA(al[1][0], bh0, a1, 0, 0, 0);
        a0 = MFMA(al[0][1], bh1, a0, 0, 0, 0); a1 = MFMA(al[1][1], bh1, a1, 0, 0, 0);
        a0 = MFMA(ah[0][0], bl0, a0, 0, 0, 0); a1 = MFMA(ah[1][0], bl0, a1, 0, 0, 0);
        a0 = MFMA(ah[0][1], bl1, a0, 0, 0, 0); a1 = MFMA(ah[1][1], bl1, a1, 0, 0, 0);
        __builtin_amdgcn_s_setprio(0);

        const int kk = q * CPB + ct * 16 + l15;
#pragma unroll
        for (int r = 0; r < 4; ++r) {
            float v;
            v = a0[r];
            m2[0][r] = __builtin_amdgcn_fmed3f(m2[0][r], m[0][r], v);
            bk[0][r] = (v > m[0][r]) ? kk : bk[0][r];
            m[0][r]  = fmaxf(m[0][r], v);
            v = a1[r];
            m2[1][r] = __builtin_amdgcn_fmed3f(m2[1][r], m[1][r], v);
            bk[1][r] = (v > m[1][r]) ? kk : bk[1][r];
            m[1][r]  = fmaxf(m[1][r], v);
        }
    }

    // ---- per-row top2 reduce across 16 col-lanes, write partials ----
#pragma unroll
    for (int rt = 0; rt < 2; ++rt)
#pragma unroll
        for (int r = 0; r < 4; ++r) {
            float mm = m[rt][r], mm2 = m2[rt][r]; int kk = bk[rt][r];
#pragma unroll
            for (int off = 1; off < 16; off <<= 1) {
                float om  = __shfl_xor(mm,  off, 64);
                float om2 = __shfl_xor(mm2, off, 64);
                int   ok  = __shfl_xor(kk,  off, 64);
                mm2 = fmaxf(fmaxf(mm2, om2), fminf(mm, om));
                if (om > mm || (om == mm && ok < kk)) { mm = om; kk = ok; }
            }
            if (l15 == 0) {
                int grow = rg * RPB + w * 32 + rt * 16 + l4 * 4 + r;
                pm [q * NROWS + grow] = mm;
                pm2[q * NROWS + grow] = mm2;
                pk [q * NROWS + grow] = kk;
            }
        }
}

// kernel 2: combine quarters -> exact re-rank of ties -> gather output + loss.
// 64 rows per block (R10-verified phase order).
__global__ __launch_bounds__(256) void vq_comb(
    const float* __restrict__ X, const float* __restrict__ E,
    const float* __restrict__ Chg,
    const float* __restrict__ pm, const float* __restrict__ pm2,
    const int* __restrict__ pk,
    float* __restrict__ out, float* __restrict__ lossp)
{
    __shared__ int   sIdx[64], sFlag[64];
    __shared__ int   sNf;
    __shared__ float sLoss[4];
    const int t = threadIdx.x, w = t >> 6, lane = t & 63;
    if (t == 0) sNf = 0;
    __syncthreads();

    const float4* Xg4 = (const float4*)X;
    const float4* Eg4 = (const float4*)E;

    // ---- phase 1: combine 4 quarter partials (one thread per row) ----
    if (t < 64) {
        int row = blockIdx.x * 64 + t;
        float top = -INFINITY, sec = -INFINITY, m2w = -INFINITY; int kw = 0;
#pragma unroll
        for (int q = 0; q < 4; ++q) {
            float mq  = pm [q * NROWS + row];
            float m2q = pm2[q * NROWS + row];
            int   kq  = pk [q * NROWS + row];
            if (mq > top) { sec = top; top = mq; kw = kq; m2w = m2q; }
            else sec = fmaxf(sec, mq);
        }
        sec = fmaxf(sec, m2w);
        sIdx[t] = kw;
        if (top - sec < TAU_S) {
            int pos = atomicAdd(&sNf, 1);
            sFlag[pos] = t;
        }
    }
    __syncthreads();

    // ---- phase 2: exact fp32 re-rank of flagged rows (one wave per row) ----
    {
        int nf = sNf;
        for (int i = w; i < nf; i += 4) {
            int lr = sFlag[i];
            size_t grow = (size_t)blockIdx.x * 64 + lr;
            const float4* xr = Xg4 + grow * 16;
            float bs = -INFINITY; int bki = 0;
#pragma unroll 1
            for (int jj = 0; jj < 16; ++jj) {
                int kq = jj * 64 + lane;
                const float4* er = Eg4 + (size_t)kq * 16;
                float a0 = 0.f, a1 = 0.f, a2 = 0.f, a3 = 0.f;
#pragma unroll
                for (int p = 0; p < 16; p += 4) {
                    float4 xv0 = xr[p],     e0 = er[p];
                    float4 xv1 = xr[p + 1], e1 = er[p + 1];
                    float4 xv2 = xr[p + 2], e2 = er[p + 2];
                    float4 xv3 = xr[p + 3], e3 = er[p + 3];
                    a0 = fmaf(xv0.x, e0.x, a0); a0 = fmaf(xv0.y, e0.y, a0);
                    a0 = fmaf(xv0.z, e0.z, a0); a0 = fmaf(xv0.w, e0.w, a0);
                    a1 = fmaf(xv1.x, e1.x, a1); a1 = fmaf(xv1.y, e1.y, a1);
                    a1 = fmaf(xv1.z, e1.z, a1); a1 = fmaf(xv1.w, e1.w, a1);
                    a2 = fmaf(xv2.x, e2.x, a2); a2 = fmaf(xv2.y, e2.y, a2);
                    a2 = fmaf(xv2.z, e2.z, a2); a2 = fmaf(xv2.w, e2.w, a2);
                    a3 = fmaf(xv3.x, e3.x, a3); a3 = fmaf(xv3.y, e3.y, a3);
                    a3 = fmaf(xv3.z, e3.z, a3); a3 = fmaf(xv3.w, e3.w, a3);
                }
                float sv = ((a0 + a1) + (a2 + a3)) - Chg[kq];
                if (sv > bs) { bs = sv; bki = kq; }
            }
#pragma unroll
            for (int off = 1; off < 64; off <<= 1) {
                float ob = __shfl_xor(bs, off, 64);
                int  okk = __shfl_xor(bki, off, 64);
                if (ob > bs || (ob == bs && okk < bki)) { bs = ob; bki = okk; }
            }
            if (lane == 0) sIdx[lr] = bki;
        }
    }
    __syncthreads();

    // ---- phase 3: output gather + loss (4 threads per row, final indices) ----
    {
        int row = t >> 2, q4 = t & 3;
        int kb = sIdx[row];
        size_t grow = (size_t)blockIdx.x * 64 + row;
        const float4* eq   = Eg4 + (size_t)kb * 16;
        const float4* xrow = Xg4 + grow * 16;
        float4* orow = (float4*)out + grow * 16;
        float ls = 0.f;
#pragma unroll
        for (int j = 0; j < 4; ++j) {
            int u = q4 * 4 + j;
            float4 qv = eq[u];
            float4 xv = xrow[u];
            orow[u] = qv;
            float dx = qv.x - xv.x; ls = fmaf(dx, dx, ls);
            float dy = qv.y - xv.y; ls = fmaf(dy, dy, ls);
            float dz = qv.z - xv.z; ls = fmaf(dz, dz, ls);
            float dw = qv.w - xv.w; ls = fmaf(dw, dw, ls);
        }
#pragma unroll
        for (int off = 32; off > 0; off >>= 1) ls += __shfl_down(ls, off, 64);
        if (lane == 0) sLoss[w] = ls;
        __syncthreads();
        if (t == 0)
            atomicAdd(lossp, (sLoss[0] + sLoss[1] + sLoss[2] + sLoss[3]) * LOSS_SCALE);
    }
}

extern "C" void kernel_launch(void* const* d_in, const int* in_sizes, int n_in,
                              void* d_out, int out_size, void* d_ws, size_t ws_size,
                              hipStream_t stream) {
    const float* X = (const float*)d_in[0];        // [64,1024,64] f32
    const float* E = (const float*)d_in[1];        // [1024,64] f32
    float* out   = (float*)d_out;
    float* lossp = out + (size_t)NROWS * D;

    // ws layout: Ch (4 KB) | Eswz (256 KB) | pm (1 MB) | pm2 (1 MB) | pk (1 MB)
    float*  Ch   = (float*)d_ws;
    bf16x8* Eswz = (bf16x8*)((char*)d_ws + 4096);
    float*  pm   = (float*)((char*)d_ws + 4096 + 262144);
    float*  pm2  = pm + (size_t)Q * NROWS;
    int*    pk   = (int*)(pm2 + (size_t)Q * NROWS);

    vq_prep<<<(K + 255) / 256, 256, 0, stream>>>(E, Ch, Eswz, lossp);

    vq_part<<<(NROWS / RPB) * Q, T1, 0, stream>>>(X, Ch, Eswz, pm, pm2, pk);

    vq_comb<<<NROWS / 64, 256, 0, stream>>>(X, E, Ch, pm, pm2, pk, out, lossp);
}